// Round 1
// baseline (428.307 us; speedup 1.0000x reference)
//
#include <hip/hip_runtime.h>
#include <math.h>

#define NB 8
#define NN 2048
#define IN_DIM 256
#define OUT_DIM 64
#define ALPHA 0.2f
#define IT 32
#define JT 64

// ---------------------------------------------------------------------------
// Kernel 1: Wh = h @ W  (16384x256 @ 256x64), plus s1 = Wh@a1, s2 = Wh@a2.
// 256 threads/block, 16 rows/block. h rows staged in LDS; W stays L1/L2-hot.
// Thread map: d = t&63 (output col), wave = t>>6 owns rows {wave+4k}.
// ---------------------------------------------------------------------------
__global__ __launch_bounds__(256) void wh_kernel(const float* __restrict__ h,
                                                 const float* __restrict__ W,
                                                 const float* __restrict__ a,
                                                 float* __restrict__ Wh,
                                                 float* __restrict__ s1,
                                                 float* __restrict__ s2) {
    __shared__ float h_lds[16 * IN_DIM];
    const int t = threadIdx.x;
    const int row0 = blockIdx.x * 16;

    // stage 16 h rows (16 KB) coalesced as float4
    const float4* hsrc = (const float4*)(h + (long)row0 * IN_DIM);
    float4* hdst = (float4*)h_lds;
    #pragma unroll
    for (int i = 0; i < 4; ++i) hdst[t + 256 * i] = hsrc[t + 256 * i];
    __syncthreads();

    const int d = t & 63;
    const int wv = t >> 6;
    float acc[4] = {0.f, 0.f, 0.f, 0.f};
    #pragma unroll 4
    for (int k = 0; k < IN_DIM; ++k) {
        float w = W[k * OUT_DIM + d];               // coalesced, L1/L2-hot
        #pragma unroll
        for (int r = 0; r < 4; ++r)
            acc[r] += h_lds[(wv + 4 * r) * IN_DIM + k] * w;  // LDS broadcast
    }

    const float a1d = a[d];
    const float a2d = a[OUT_DIM + d];
    #pragma unroll
    for (int r = 0; r < 4; ++r) {
        const int grow = row0 + wv + 4 * r;
        Wh[(long)grow * OUT_DIM + d] = acc[r];
        float v1 = acc[r] * a1d;
        float v2 = acc[r] * a2d;
        #pragma unroll
        for (int off = 32; off > 0; off >>= 1) {
            v1 += __shfl_xor(v1, off, 64);
            v2 += __shfl_xor(v2, off, 64);
        }
        if (d == 0) { s1[grow] = v1; s2[grow] = v2; }
    }
}

// ---------------------------------------------------------------------------
// Kernel 2: fused masked-softmax + attn@Wh, flash-style, NO max subtraction
// (e = leakyrelu(s1+s2) <= ~6, exp never overflows; masked entries -> p=0).
// Block: 256 threads, i-tile = 32 rows, j-tile = 64.
//  Phase A: lane=j streams adj tile, p -> LDS (stride 65), wave row-sums -> l.
//  Phase B: 2 rows x 4 cols per thread, float4 Wh loads (L2-hot).
// ---------------------------------------------------------------------------
__global__ __launch_bounds__(256) void attn_kernel(const int* __restrict__ adj,
                                                   const float* __restrict__ Wh,
                                                   const float* __restrict__ s1,
                                                   const float* __restrict__ s2,
                                                   float* __restrict__ out) {
    __shared__ float p_lds[IT * 65];   // [row][j], stride 65: conflict-free
    __shared__ float l_lds[IT];
    __shared__ float s1_lds[IT];

    const int t = threadIdx.x;
    const int b = blockIdx.x >> 6;            // 64 i-tiles per batch
    const int i0 = (blockIdx.x & 63) * IT;

    if (t < IT) {
        l_lds[t] = 0.f;
        s1_lds[t] = s1[b * NN + i0 + t];
    }
    __syncthreads();

    const int lane = t & 63;
    const int wv = t >> 6;                    // wave id 0..3
    const int r0 = (t >> 4) << 1;             // phase-B rows r0, r0+1 (0..30)
    const int d0 = (t & 15) << 2;             // phase-B cols d0..d0+3

    float acc0[4] = {0.f, 0.f, 0.f, 0.f};
    float acc1[4] = {0.f, 0.f, 0.f, 0.f};

    const long adj_base = (long)b * NN * NN + (long)i0 * NN;
    const float* WhB = Wh + (long)b * NN * OUT_DIM;
    const float* s2B = s2 + b * NN;

    for (int jt = 0; jt < NN / JT; ++jt) {
        const int j0 = jt * JT;

        // ---- Phase A: scores -> p, row sums -> l ----
        const float s2v = s2B[j0 + lane];
        int av[IT / 4];
        #pragma unroll
        for (int k = 0; k < IT / 4; ++k) {    // 8 rows per wave, ILP on loads
            const int r = wv + 4 * k;
            av[k] = adj[adj_base + (long)r * NN + j0 + lane];
        }
        #pragma unroll
        for (int k = 0; k < IT / 4; ++k) {
            const int r = wv + 4 * k;
            float e = s1_lds[r] + s2v;
            e = e > 0.f ? e : ALPHA * e;
            float p = (av[k] != 0) ? __expf(e) : 0.f;
            p_lds[r * 65 + lane] = p;
            float sum = p;
            #pragma unroll
            for (int off = 32; off > 0; off >>= 1)
                sum += __shfl_xor(sum, off, 64);
            if (lane == 0) l_lds[r] += sum;   // waves own disjoint rows
        }
        __syncthreads();

        // ---- Phase B: acc += P_tile @ Wh_tile ----
        const float4* wp = (const float4*)(WhB + (long)j0 * OUT_DIM + d0);
        #pragma unroll 4
        for (int j = 0; j < JT; ++j) {
            const float4 w4 = wp[j * (OUT_DIM / 4)];
            const float p0 = p_lds[r0 * 65 + j];
            const float p1 = p_lds[(r0 + 1) * 65 + j];
            acc0[0] += p0 * w4.x; acc0[1] += p0 * w4.y;
            acc0[2] += p0 * w4.z; acc0[3] += p0 * w4.w;
            acc1[0] += p1 * w4.x; acc1[1] += p1 * w4.y;
            acc1[2] += p1 * w4.z; acc1[3] += p1 * w4.w;
        }
        __syncthreads();
    }

    // ---- Epilogue: normalize and store ----
    const float inv0 = 1.f / l_lds[r0];
    const float inv1 = 1.f / l_lds[r0 + 1];
    float4* op = (float4*)(out + (long)(b * NN + i0) * OUT_DIM);
    float4 o0, o1;
    o0.x = acc0[0] * inv0; o0.y = acc0[1] * inv0;
    o0.z = acc0[2] * inv0; o0.w = acc0[3] * inv0;
    o1.x = acc1[0] * inv1; o1.y = acc1[1] * inv1;
    o1.z = acc1[2] * inv1; o1.w = acc1[3] * inv1;
    op[r0 * (OUT_DIM / 4) + (d0 >> 2)] = o0;
    op[(r0 + 1) * (OUT_DIM / 4) + (d0 >> 2)] = o1;
}

// ---------------------------------------------------------------------------
extern "C" void kernel_launch(void* const* d_in, const int* in_sizes, int n_in,
                              void* d_out, int out_size, void* d_ws, size_t ws_size,
                              hipStream_t stream) {
    const float* h   = (const float*)d_in[0];
    const int*   adj = (const int*)d_in[1];
    const float* W   = (const float*)d_in[2];
    const float* a   = (const float*)d_in[3];
    float* out = (float*)d_out;

    float* Wh = (float*)d_ws;                  // 16384*64 f32 = 4 MB
    float* s1 = Wh + (long)NB * NN * OUT_DIM;  // 16384 f32
    float* s2 = s1 + NB * NN;                  // 16384 f32

    wh_kernel<<<NB * NN / 16, 256, 0, stream>>>(h, W, a, Wh, s1, s2);
    attn_kernel<<<NB * (NN / IT), 256, 0, stream>>>(adj, Wh, s1, s2, out);
}